// Round 11
// baseline (953.527 us; speedup 1.0000x reference)
//
#include <hip/hip_runtime.h>

// Problem constants (B=4, N=2048, C=256, H=8, D=32, keep = int(2048*0.3) = 614)
#define BDIM 4
#define NSEQ 2048
#define CDIM 256
#define NHEADS 8
#define QB 4                     // query rows per block (1 per wave)
#define NT2 32                   // per-wave tiles: 32 tiles x 16 rows = 512 cols
#define NKEEP 614                // int(2048 * (1.0 - 0.7))
#define SSTR 2056                // sbuf row stride (bank stagger)
#define CAP 640                  // kept-index list capacity per row (>= 614 + tie margin)
#define ATTN_SCALE 0.17677669529663688f  // 32^-0.5

typedef unsigned long long ull;

__device__ float colsumG[BDIM * NHEADS * 32];   // per-(b,h) column sum of V

// -------------------------------------------------------------------------
// GEMM: C[M][Nt] = A[M][K] @ W[Nt][K]^T + bias[Nt]   (unchanged, validated)
// -------------------------------------------------------------------------
__global__ __launch_bounds__(256) void gemm_nt_bias(
    const float* __restrict__ A, const float* __restrict__ W,
    const float* __restrict__ bias, float* __restrict__ C,
    int M, int Nt, int K)
{
    __shared__ __align__(16) float As[32][68];
    __shared__ __align__(16) float Ws[32][68];
    const int tid = threadIdx.x;
    const int bm = blockIdx.x * 64;
    const int bn = blockIdx.y * 64;
    const int tm = tid >> 4;
    const int tn = tid & 15;
    const int lr = tid >> 2;
    const int lq = tid & 3;
    const float* Ap = A + (size_t)(bm + lr) * K + lq * 8;
    const float* Wp = W + (size_t)(bn + lr) * K + lq * 8;
    float acc[4][4] = {};

    for (int k0 = 0; k0 < K; k0 += 32) {
        float4 a0 = *(const float4*)(Ap + k0);
        float4 a1 = *(const float4*)(Ap + k0 + 4);
        float4 w0 = *(const float4*)(Wp + k0);
        float4 w1 = *(const float4*)(Wp + k0 + 4);
        __syncthreads();
        const int kq = lq * 8;
        As[kq+0][lr]=a0.x; As[kq+1][lr]=a0.y; As[kq+2][lr]=a0.z; As[kq+3][lr]=a0.w;
        As[kq+4][lr]=a1.x; As[kq+5][lr]=a1.y; As[kq+6][lr]=a1.z; As[kq+7][lr]=a1.w;
        Ws[kq+0][lr]=w0.x; Ws[kq+1][lr]=w0.y; Ws[kq+2][lr]=w0.z; Ws[kq+3][lr]=w0.w;
        Ws[kq+4][lr]=w1.x; Ws[kq+5][lr]=w1.y; Ws[kq+6][lr]=w1.z; Ws[kq+7][lr]=w1.w;
        __syncthreads();
        #pragma unroll
        for (int k = 0; k < 32; ++k) {
            float4 av = *(const float4*)&As[k][tm*4];
            float4 wv = *(const float4*)&Ws[k][tn*4];
            acc[0][0] += av.x*wv.x; acc[0][1] += av.x*wv.y; acc[0][2] += av.x*wv.z; acc[0][3] += av.x*wv.w;
            acc[1][0] += av.y*wv.x; acc[1][1] += av.y*wv.y; acc[1][2] += av.y*wv.z; acc[1][3] += av.y*wv.w;
            acc[2][0] += av.z*wv.x; acc[2][1] += av.z*wv.y; acc[2][2] += av.z*wv.z; acc[2][3] += av.z*wv.w;
            acc[3][0] += av.w*wv.x; acc[3][1] += av.w*wv.y; acc[3][2] += av.w*wv.z; acc[3][3] += av.w*wv.w;
        }
    }
    float4 bb = *(const float4*)(bias + bn + tn*4);
    #pragma unroll
    for (int i = 0; i < 4; ++i) {
        float4 o;
        o.x = acc[i][0] + bb.x;
        o.y = acc[i][1] + bb.y;
        o.z = acc[i][2] + bb.z;
        o.w = acc[i][3] + bb.w;
        *(float4*)(C + (size_t)(bm + tm*4 + i) * Nt + bn + tn*4) = o;
    }
}

// -------------------------------------------------------------------------
// V column-sum per (b,h): colsumG[bh][d] = sum_n V[b,n,h,d]
// -------------------------------------------------------------------------
__global__ __launch_bounds__(256) void vcolsum(const float* __restrict__ qkv)
{
    const int bh = blockIdx.x;
    const int bb = bh >> 3, hh = bh & 7;
    const int g = threadIdx.x >> 5, d = threadIdx.x & 31;
    const float* vp = qkv + (size_t)bb * NSEQ * 768 + 512 + hh * 32 + d;
    const int nbase = g * 256;
    float s0 = 0.f, s1 = 0.f, s2 = 0.f, s3 = 0.f;
    #pragma unroll 4
    for (int n = 0; n < 256; n += 4) {
        s0 += vp[(size_t)(nbase + n    ) * 768];
        s1 += vp[(size_t)(nbase + n + 1) * 768];
        s2 += vp[(size_t)(nbase + n + 2) * 768];
        s3 += vp[(size_t)(nbase + n + 3) * 768];
    }
    __shared__ float red[8][32];
    red[g][d] = (s0 + s1) + (s2 + s3);
    __syncthreads();
    if (threadIdx.x < 32) {
        float t = 0.f;
        #pragma unroll
        for (int gg = 0; gg < 8; ++gg) t += red[gg][threadIdx.x];
        colsumG[bh * 32 + threadIdx.x] = t;
    }
}

// -------------------------------------------------------------------------
// Fused sparse attention — per-wave streaming QK (unchanged), exact radix
// select (packed u16 histogram), ballot-compacted kept-index list, and
// SPARSE PV: out = sum_kept (exp(s-mx)-cm) v + cm*colsum;
//            Z   = sum_kept (exp(s-mx)-cm) + 2048*cm.   (exact, tie-safe)
// 2 block barriers total.
// -------------------------------------------------------------------------
__device__ __forceinline__ unsigned int f2key(float f) {
    unsigned int u = __float_as_uint(f);
    return (u & 0x80000000u) ? ~u : (u | 0x80000000u);  // monotone order-preserving
}
__device__ __forceinline__ float dpp_xor1_add(float x) {
    int s = __builtin_amdgcn_mov_dpp(__float_as_int(x), 0xB1, 0xF, 0xF, true);
    return x + __int_as_float(s);
}
__device__ __forceinline__ float dpp_xor2_add(float x) {
    int s = __builtin_amdgcn_mov_dpp(__float_as_int(x), 0x4E, 0xF, 0xF, true);
    return x + __int_as_float(s);
}
__device__ __forceinline__ unsigned lanecnt_lt(ull m) {
    return __builtin_amdgcn_mbcnt_hi((unsigned)(m >> 32),
           __builtin_amdgcn_mbcnt_lo((unsigned)(m & 0xFFFFFFFFull), 0u));
}

#define RBAR() do { asm volatile("s_waitcnt lgkmcnt(0)" ::: "memory"); \
                    __builtin_amdgcn_s_barrier();                      \
                    asm volatile("" ::: "memory"); } while (0)
#define LGKM0() asm volatile("s_waitcnt lgkmcnt(0)" ::: "memory")

__global__ __launch_bounds__(256, 4) void sparse_attn(
    const float* __restrict__ qkv, float* __restrict__ aout)
{
    __shared__ __align__(16) float sbuf[QB * SSTR];          // 32.9 KB scores
    __shared__ __align__(16) unsigned int histw[QB * 128];   // 2 KB packed (2 bins/word)
    __shared__ __align__(16) unsigned short idxb[QB * CAP];  // 5 KB kept indices
    __shared__ unsigned int prefS[QB];
    __shared__ int remS[QB];

    const int tid = threadIdx.x;
    const int w   = tid >> 6;       // wave id = row id = column-range owner
    const int l   = tid & 63;
    const int p   = l & 3;          // dim-chunk pair (8 floats at 8p)
    const int jg  = l >> 2;         // 0..15 = row within a 16-row tile

    const int blk = blockIdx.x;
    const int nqb = NSEQ / QB;      // 512
    const int bh  = blk / nqb;
    const int qblk = blk % nqb;
    const int b = bh / NHEADS, h = bh % NHEADS;
    const int n0 = qblk * QB;

    const float* base = qkv + (size_t)b * NSEQ * 768;
    const float* kptr = base + 256 + h * 32 + p * 8 + (size_t)((w << 9) + jg) * 768;
#define KADDR(t) (kptr + (size_t)(t) * (16 * 768))

    // ---- Q rows 0..3, this lane's 8-dim chunk, pre-scaled, in registers ----
    float4 qa[QB], qc[QB];
    {
        const float* gq = base + (size_t)n0 * 768 + h * 32 + p * 8;
        #pragma unroll
        for (int r = 0; r < QB; ++r) {
            float4 x0 = *(const float4*)(gq + (size_t)r * 768);
            float4 x1 = *(const float4*)(gq + (size_t)r * 768 + 4);
            qa[r].x = x0.x * ATTN_SCALE; qa[r].y = x0.y * ATTN_SCALE;
            qa[r].z = x0.z * ATTN_SCALE; qa[r].w = x0.w * ATTN_SCALE;
            qc[r].x = x1.x * ATTN_SCALE; qc[r].y = x1.y * ATTN_SCALE;
            qc[r].z = x1.z * ATTN_SCALE; qc[r].w = x1.w * ATTN_SCALE;
        }
    }
    ((uint2*)histw)[tid] = make_uint2(0u, 0u);   // 256 x 8B = 2 KB exact
    if (tid < QB) { prefS[tid] = 0u; remS[tid] = NKEEP; }
    RBAR();   // barrier 1: histw/prefS initialized before any atomic

#define QK_TILE(K0, K1, T) do {                                               \
        float sc0 = qa[0].x*(K0).x + qa[0].y*(K0).y + qa[0].z*(K0).z + qa[0].w*(K0).w \
                  + qc[0].x*(K1).x + qc[0].y*(K1).y + qc[0].z*(K1).z + qc[0].w*(K1).w; \
        float sc1 = qa[1].x*(K0).x + qa[1].y*(K0).y + qa[1].z*(K0).z + qa[1].w*(K0).w \
                  + qc[1].x*(K1).x + qc[1].y*(K1).y + qc[1].z*(K1).z + qc[1].w*(K1).w; \
        float sc2 = qa[2].x*(K0).x + qa[2].y*(K0).y + qa[2].z*(K0).z + qa[2].w*(K0).w \
                  + qc[2].x*(K1).x + qc[2].y*(K1).y + qc[2].z*(K1).z + qc[2].w*(K1).w; \
        float sc3 = qa[3].x*(K0).x + qa[3].y*(K0).y + qa[3].z*(K0).z + qa[3].w*(K0).w \
                  + qc[3].x*(K1).x + qc[3].y*(K1).y + qc[3].z*(K1).z + qc[3].w*(K1).w; \
        sc0 = dpp_xor2_add(dpp_xor1_add(sc0));                                \
        sc1 = dpp_xor2_add(dpp_xor1_add(sc1));                                \
        sc2 = dpp_xor2_add(dpp_xor1_add(sc2));                                \
        sc3 = dpp_xor2_add(dpp_xor1_add(sc3));                                \
        float myv = (p == 0) ? sc0 : (p == 1) ? sc1 : (p == 2) ? sc2 : sc3;   \
        const int col = (w << 9) + ((T) << 4) + jg;                           \
        sbuf[p * SSTR + col] = myv;                                           \
        unsigned kk = f2key(myv);                                             \
        atomicAdd(&histw[p * 128 + (kk >> 25)], 1u << (((kk >> 24) & 1u) * 16)); \
    } while (0)

    // ---- Phase B: scores + top-byte histogram. 4-deep register pipeline. ----
    float4 ka0 = *(const float4*)(KADDR(0)), ka1 = *(const float4*)(KADDR(0) + 4);
    float4 kb0 = *(const float4*)(KADDR(1)), kb1 = *(const float4*)(KADDR(1) + 4);
    float4 kc0 = *(const float4*)(KADDR(2)), kc1 = *(const float4*)(KADDR(2) + 4);
    float4 kd0 = *(const float4*)(KADDR(3)), kd1 = *(const float4*)(KADDR(3) + 4);
    #pragma unroll 1
    for (int t = 0; t < NT2; t += 4) {
        float4 c0, c1;
        c0 = ka0; c1 = ka1;
        if (t + 4 < NT2) { ka0 = *(const float4*)(KADDR(t + 4)); ka1 = *(const float4*)(KADDR(t + 4) + 4); }
        QK_TILE(c0, c1, t);
        c0 = kb0; c1 = kb1;
        if (t + 5 < NT2) { kb0 = *(const float4*)(KADDR(t + 5)); kb1 = *(const float4*)(KADDR(t + 5) + 4); }
        QK_TILE(c0, c1, t + 1);
        c0 = kc0; c1 = kc1;
        if (t + 6 < NT2) { kc0 = *(const float4*)(KADDR(t + 6)); kc1 = *(const float4*)(KADDR(t + 6) + 4); }
        QK_TILE(c0, c1, t + 2);
        c0 = kd0; c1 = kd1;
        if (t + 7 < NT2) { kd0 = *(const float4*)(KADDR(t + 7)); kd1 = *(const float4*)(KADDR(t + 7) + 4); }
        QK_TILE(c0, c1, t + 3);
    }
    RBAR();   // barrier 2: all scores + histogram atomics visible

    // ---- Phase C: exact 614th-largest per row. Wave w owns row w only. ----
    const int myrowbase = w * SSTR;
    unsigned int* hroww = histw + w * 128;
    #pragma unroll 1
    for (int pass = 3; pass >= 0; --pass) {
        const int sh = pass * 8;
        const unsigned int pr = prefS[w];
        const int remv = remS[w];
        if (pass != 3) {
            const unsigned int hmsk = 0xFFFFFFFFu << (sh + 8);
            *(uint2*)(hroww + 2 * l) = make_uint2(0u, 0u);
            LGKM0();
            #pragma unroll 2
            for (int e = 0; e < 8; ++e) {
                float4 v = *(const float4*)&sbuf[myrowbase + l * 4 + 256 * e];
                unsigned int k0 = f2key(v.x), k1 = f2key(v.y), k2 = f2key(v.z), k3 = f2key(v.w);
                if ((k0 & hmsk) == pr) { unsigned bn = (k0 >> sh) & 255u; atomicAdd(&hroww[bn >> 1], 1u << ((bn & 1u) * 16)); }
                if ((k1 & hmsk) == pr) { unsigned bn = (k1 >> sh) & 255u; atomicAdd(&hroww[bn >> 1], 1u << ((bn & 1u) * 16)); }
                if ((k2 & hmsk) == pr) { unsigned bn = (k2 >> sh) & 255u; atomicAdd(&hroww[bn >> 1], 1u << ((bn & 1u) * 16)); }
                if ((k3 & hmsk) == pr) { unsigned bn = (k3 >> sh) & 255u; atomicAdd(&hroww[bn >> 1], 1u << ((bn & 1u) * 16)); }
            }
            LGKM0();
        }
        uint2 cw = *(const uint2*)(hroww + 2 * l);
        unsigned int cnt[4] = { cw.x & 0xFFFFu, cw.x >> 16, cw.y & 0xFFFFu, cw.y >> 16 };
        unsigned int part = cnt[0] + cnt[1] + cnt[2] + cnt[3];
        unsigned int suf = part;
        #pragma unroll
        for (int dlt = 1; dlt < 64; dlt <<= 1) {
            unsigned int v = __shfl_down(suf, dlt);
            if (l + dlt < 64) suf += v;
        }
        unsigned int run = suf - part;   // elems in bins owned by lanes > l
        #pragma unroll
        for (int i = 3; i >= 0; --i) {
            if ((int)run < remv && remv <= (int)(run + cnt[i])) {
                remS[w]  = remv - (int)run;
                prefS[w] = pr | ((unsigned int)(l * 4 + i) << sh);
            }
            run += cnt[i];
        }
        LGKM0();  // pref/rem visible wave-wide before next pass
    }

    // ---- Phase D: mask stats + ballot-compacted kept-index list (row w) ----
    float mx = 0.f;
    unsigned int cbase = 0;
    {
        unsigned int key = prefS[w];
        unsigned int uu = (key & 0x80000000u) ? (key & 0x7FFFFFFFu) : ~key;
        const float thr = __uint_as_float(uu);
        #pragma unroll 2
        for (int e = 0; e < 8; ++e) {
            float4 v = *(const float4*)&sbuf[myrowbase + l * 4 + 256 * e];
            const int col0 = 256 * e + l * 4;
            bool k0 = (v.x >= thr), k1 = (v.y >= thr), k2 = (v.z >= thr), k3 = (v.w >= thr);
            mx = fmaxf(mx, fmaxf(fmaxf(k0 ? v.x : 0.f, k1 ? v.y : 0.f),
                                 fmaxf(k2 ? v.z : 0.f, k3 ? v.w : 0.f)));
            ull m;
            m = __ballot(k0);
            if (k0) { unsigned pos = cbase + lanecnt_lt(m); if (pos < CAP) idxb[w * CAP + pos] = (unsigned short)(col0 + 0); }
            cbase += (unsigned)__popcll(m);
            m = __ballot(k1);
            if (k1) { unsigned pos = cbase + lanecnt_lt(m); if (pos < CAP) idxb[w * CAP + pos] = (unsigned short)(col0 + 1); }
            cbase += (unsigned)__popcll(m);
            m = __ballot(k2);
            if (k2) { unsigned pos = cbase + lanecnt_lt(m); if (pos < CAP) idxb[w * CAP + pos] = (unsigned short)(col0 + 2); }
            cbase += (unsigned)__popcll(m);
            m = __ballot(k3);
            if (k3) { unsigned pos = cbase + lanecnt_lt(m); if (pos < CAP) idxb[w * CAP + pos] = (unsigned short)(col0 + 3); }
            cbase += (unsigned)__popcll(m);
        }
    }
    #pragma unroll
    for (int d2 = 32; d2 >= 1; d2 >>= 1) mx = fmaxf(mx, __shfl_xor(mx, d2));
    const float cm = __expf(-mx);
    const int L = (cbase < (unsigned)CAP) ? (int)cbase : CAP;
    LGKM0();   // own idxb writes complete before reads

    // ---- Phase E: sparse PV gather (row w), 2-slot register pipeline ----
    const float* vbase = base + 512 + h * 32;
    float4 A0, A1, A2, A3, A4, A5, A6, A7;
    A0.x=0;A0.y=0;A0.z=0;A0.w=0; A1=A0;A2=A0;A3=A0;A4=A0;A5=A0;A6=A0;A7=A0;
    float z = 0.f;
    const int Lpad = (L + 63) & ~63;

#define VGATH(X, vc) do {                                                        \
        X##0 = *(const float4*)(vc);        X##1 = *(const float4*)((vc) + 4);   \
        X##2 = *(const float4*)((vc) + 8);  X##3 = *(const float4*)((vc) + 12);  \
        X##4 = *(const float4*)((vc) + 16); X##5 = *(const float4*)((vc) + 20);  \
        X##6 = *(const float4*)((vc) + 24); X##7 = *(const float4*)((vc) + 28);  \
    } while (0)
#define PVFMA(pp, X) do {                                                                                             \
        A0.x=fmaf(pp,(X##0).x,A0.x); A0.y=fmaf(pp,(X##0).y,A0.y); A0.z=fmaf(pp,(X##0).z,A0.z); A0.w=fmaf(pp,(X##0).w,A0.w); \
        A1.x=fmaf(pp,(X##1).x,A1.x); A1.y=fmaf(pp,(X##1).y,A1.y); A1.z=fmaf(pp,(X##1).z,A1.z); A1.w=fmaf(pp,(X##1).w,A1.w); \
        A2.x=fmaf(pp,(X##2).x,A2.x); A2.y=fmaf(pp,(X##2).y,A2.y); A2.z=fmaf(pp,(X##2).z,A2.z); A2.w=fmaf(pp,(X##2).w,A2.w); \
        A3.x=fmaf(pp,(X##3).x,A3.x); A3.y=fmaf(pp,(X##3).y,A3.y); A3.z=fmaf(pp,(X##3).z,A3.z); A3.w=fmaf(pp,(X##3).w,A3.w); \
        A4.x=fmaf(pp,(X##4).x,A4.x); A4.y=fmaf(pp,(X##4).y,A4.y); A4.z=fmaf(pp,(X##4).z,A4.z); A4.w=fmaf(pp,(X##4).w,A4.w); \
        A5.x=fmaf(pp,(X##5).x,A5.x); A5.y=fmaf(pp,(X##5).y,A5.y); A5.z=fmaf(pp,(X##5).z,A5.z); A5.w=fmaf(pp,(X##5).w,A5.w); \
        A6.x=fmaf(pp,(X##6).x,A6.x); A6.y=fmaf(pp,(X##6).y,A6.y); A6.z=fmaf(pp,(X##6).z,A6.z); A6.w=fmaf(pp,(X##6).w,A6.w); \
        A7.x=fmaf(pp,(X##7).x,A7.x); A7.y=fmaf(pp,(X##7).y,A7.y); A7.z=fmaf(pp,(X##7).z,A7.z); A7.w=fmaf(pp,(X##7).w,A7.w); \
    } while (0)

    bool actA = l < L;
    int idxA = idxb[w * CAP + (actA ? l : 0)];
    float svA = sbuf[myrowbase + idxA];
    float4 xA0, xA1, xA2, xA3, xA4, xA5, xA6, xA7;
    { const float* vcA = vbase + (size_t)idxA * 768; VGATH(xA, vcA); }
    #pragma unroll 1
    for (int i = l; i < Lpad; i += 128) {
        const int ib = i + 64;
        const bool actB = ib < L;
        const int idxB = idxb[w * CAP + (actB ? ib : 0)];
        const float svB = sbuf[myrowbase + idxB];
        float4 xB0, xB1, xB2, xB3, xB4, xB5, xB6, xB7;
        { const float* vcB = vbase + (size_t)idxB * 768; VGATH(xB, vcB); }
        float ppA = actA ? (__expf(svA - mx) - cm) : 0.f;
        z += ppA;
        PVFMA(ppA, xA);
        const int ia = i + 128;
        actA = ia < L;
        idxA = idxb[w * CAP + (actA ? ia : 0)];
        svA = sbuf[myrowbase + idxA];
        { const float* vcA = vbase + (size_t)idxA * 768; VGATH(xA, vcA); }
        float ppB = actB ? (__expf(svB - mx) - cm) : 0.f;
        z += ppB;
        PVFMA(ppB, xB);
    }

    // ---- wave-wide butterfly reduce of z and the 32 accumulators ----
    #pragma unroll
    for (int d2 = 1; d2 <= 32; d2 <<= 1) {
        z += __shfl_xor(z, d2);
        A0.x += __shfl_xor(A0.x, d2); A0.y += __shfl_xor(A0.y, d2); A0.z += __shfl_xor(A0.z, d2); A0.w += __shfl_xor(A0.w, d2);
        A1.x += __shfl_xor(A1.x, d2); A1.y += __shfl_xor(A1.y, d2); A1.z += __shfl_xor(A1.z, d2); A1.w += __shfl_xor(A1.w, d2);
        A2.x += __shfl_xor(A2.x, d2); A2.y += __shfl_xor(A2.y, d2); A2.z += __shfl_xor(A2.z, d2); A2.w += __shfl_xor(A2.w, d2);
        A3.x += __shfl_xor(A3.x, d2); A3.y += __shfl_xor(A3.y, d2); A3.z += __shfl_xor(A3.z, d2); A3.w += __shfl_xor(A3.w, d2);
        A4.x += __shfl_xor(A4.x, d2); A4.y += __shfl_xor(A4.y, d2); A4.z += __shfl_xor(A4.z, d2); A4.w += __shfl_xor(A4.w, d2);
        A5.x += __shfl_xor(A5.x, d2); A5.y += __shfl_xor(A5.y, d2); A5.z += __shfl_xor(A5.z, d2); A5.w += __shfl_xor(A5.w, d2);
        A6.x += __shfl_xor(A6.x, d2); A6.y += __shfl_xor(A6.y, d2); A6.z += __shfl_xor(A6.z, d2); A6.w += __shfl_xor(A6.w, d2);
        A7.x += __shfl_xor(A7.x, d2); A7.y += __shfl_xor(A7.y, d2); A7.z += __shfl_xor(A7.z, d2); A7.w += __shfl_xor(A7.w, d2);
    }
    if (l < 32) {
        float val = 0.f;
#define PICK(q, Aq) \
        if (l == 4*q+0) val = (Aq).x; \
        if (l == 4*q+1) val = (Aq).y; \
        if (l == 4*q+2) val = (Aq).z; \
        if (l == 4*q+3) val = (Aq).w;
        PICK(0, A0) PICK(1, A1) PICK(2, A2) PICK(3, A3)
        PICK(4, A4) PICK(5, A5) PICK(6, A6) PICK(7, A7)
#undef PICK
        const float Zt = z + 2048.f * cm;
        const float cs = colsumG[(b * NHEADS + h) * 32 + l];
        aout[((size_t)b * NSEQ + n0 + w) * CDIM + h * 32 + l] = (val + cm * cs) / Zt;
    }
}

// -------------------------------------------------------------------------
extern "C" void kernel_launch(void* const* d_in, const int* in_sizes, int n_in,
                              void* d_out, int out_size, void* d_ws, size_t ws_size,
                              hipStream_t stream) {
    (void)in_sizes; (void)n_in; (void)out_size; (void)ws_size;
    const float* x      = (const float*)d_in[0];
    const float* w_qkv  = (const float*)d_in[1];
    const float* b_qkv  = (const float*)d_in[2];
    const float* w_proj = (const float*)d_in[3];
    const float* b_proj = (const float*)d_in[4];
    float* out = (float*)d_out;

    const int M = BDIM * NSEQ;  // 8192
    float* qkv_ws  = (float*)d_ws;                       // 25.2 MB
    float* attn_ws = qkv_ws + (size_t)M * 768;           // 8.4 MB

    // 1) QKV GEMM -> [B][N][3][H][D]
    dim3 g1(M / 64, 768 / 64);
    gemm_nt_bias<<<g1, 256, 0, stream>>>(x, w_qkv, b_qkv, qkv_ws, M, 768, 256);

    // 1b) V column sums per (b,h)
    vcolsum<<<BDIM * NHEADS, 256, 0, stream>>>(qkv_ws);

    // 2) fused sparse attention -> [B][N][C]
    sparse_attn<<<BDIM * NHEADS * (NSEQ / QB), 256, 0, stream>>>(qkv_ws, attn_ws);

    // 3) projection GEMM -> d_out
    dim3 g2(M / 64, 256 / 64);
    gemm_nt_bias<<<g2, 256, 0, stream>>>(attn_ws, w_proj, b_proj, out, M, 256, 256);
}

// Round 12
// 653.874 us; speedup vs baseline: 1.4583x; 1.4583x over previous
//
#include <hip/hip_runtime.h>

// Problem constants (B=4, N=2048, C=256, H=8, D=32, keep = int(2048*0.3) = 614)
#define BDIM 4
#define NSEQ 2048
#define CDIM 256
#define NHEADS 8
#define QB 4                     // query rows per block (1 per wave)
#define NT2 32                   // per-wave tiles: 32 tiles x 16 rows = 512 cols
#define NKEEP 614                // int(2048 * (1.0 - 0.7))
#define SSTR 2056                // sbuf row stride (bank stagger)
#define ATTN_SCALE 0.17677669529663688f  // 32^-0.5

// -------------------------------------------------------------------------
// GEMM: C[M][Nt] = A[M][K] @ W[Nt][K]^T + bias[Nt]   (unchanged, validated)
// -------------------------------------------------------------------------
__global__ __launch_bounds__(256) void gemm_nt_bias(
    const float* __restrict__ A, const float* __restrict__ W,
    const float* __restrict__ bias, float* __restrict__ C,
    int M, int Nt, int K)
{
    __shared__ __align__(16) float As[32][68];
    __shared__ __align__(16) float Ws[32][68];
    const int tid = threadIdx.x;
    const int bm = blockIdx.x * 64;
    const int bn = blockIdx.y * 64;
    const int tm = tid >> 4;
    const int tn = tid & 15;
    const int lr = tid >> 2;
    const int lq = tid & 3;
    const float* Ap = A + (size_t)(bm + lr) * K + lq * 8;
    const float* Wp = W + (size_t)(bn + lr) * K + lq * 8;
    float acc[4][4] = {};

    for (int k0 = 0; k0 < K; k0 += 32) {
        float4 a0 = *(const float4*)(Ap + k0);
        float4 a1 = *(const float4*)(Ap + k0 + 4);
        float4 w0 = *(const float4*)(Wp + k0);
        float4 w1 = *(const float4*)(Wp + k0 + 4);
        __syncthreads();
        const int kq = lq * 8;
        As[kq+0][lr]=a0.x; As[kq+1][lr]=a0.y; As[kq+2][lr]=a0.z; As[kq+3][lr]=a0.w;
        As[kq+4][lr]=a1.x; As[kq+5][lr]=a1.y; As[kq+6][lr]=a1.z; As[kq+7][lr]=a1.w;
        Ws[kq+0][lr]=w0.x; Ws[kq+1][lr]=w0.y; Ws[kq+2][lr]=w0.z; Ws[kq+3][lr]=w0.w;
        Ws[kq+4][lr]=w1.x; Ws[kq+5][lr]=w1.y; Ws[kq+6][lr]=w1.z; Ws[kq+7][lr]=w1.w;
        __syncthreads();
        #pragma unroll
        for (int k = 0; k < 32; ++k) {
            float4 av = *(const float4*)&As[k][tm*4];
            float4 wv = *(const float4*)&Ws[k][tn*4];
            acc[0][0] += av.x*wv.x; acc[0][1] += av.x*wv.y; acc[0][2] += av.x*wv.z; acc[0][3] += av.x*wv.w;
            acc[1][0] += av.y*wv.x; acc[1][1] += av.y*wv.y; acc[1][2] += av.y*wv.z; acc[1][3] += av.y*wv.w;
            acc[2][0] += av.z*wv.x; acc[2][1] += av.z*wv.y; acc[2][2] += av.z*wv.z; acc[2][3] += av.z*wv.w;
            acc[3][0] += av.w*wv.x; acc[3][1] += av.w*wv.y; acc[3][2] += av.w*wv.z; acc[3][3] += av.w*wv.w;
        }
    }
    float4 bb = *(const float4*)(bias + bn + tn*4);
    #pragma unroll
    for (int i = 0; i < 4; ++i) {
        float4 o;
        o.x = acc[i][0] + bb.x;
        o.y = acc[i][1] + bb.y;
        o.z = acc[i][2] + bb.z;
        o.w = acc[i][3] + bb.w;
        *(float4*)(C + (size_t)(bm + tm*4 + i) * Nt + bn + tn*4) = o;
    }
}

// -------------------------------------------------------------------------
// Fused sparse attention — per-wave streaming, K/V direct global->register,
// COALESCED quad partition: lane p of a quad owns dims [4p,4p+4) and
// [16+4p,16+4p+4), so each 64-lane dwordx4 covers 16 contiguous 64B
// segments (was 64 scattered 16B pieces). Math identical to round 9.
// -------------------------------------------------------------------------
__device__ __forceinline__ unsigned int f2key(float f) {
    unsigned int u = __float_as_uint(f);
    return (u & 0x80000000u) ? ~u : (u | 0x80000000u);  // monotone order-preserving
}
__device__ __forceinline__ float dpp_xor1_add(float x) {
    int s = __builtin_amdgcn_mov_dpp(__float_as_int(x), 0xB1, 0xF, 0xF, true);
    return x + __int_as_float(s);
}
__device__ __forceinline__ float dpp_xor2_add(float x) {
    int s = __builtin_amdgcn_mov_dpp(__float_as_int(x), 0x4E, 0xF, 0xF, true);
    return x + __int_as_float(s);
}

#define RBAR() do { asm volatile("s_waitcnt lgkmcnt(0)" ::: "memory"); \
                    __builtin_amdgcn_s_barrier();                      \
                    asm volatile("" ::: "memory"); } while (0)
#define LGKM0() asm volatile("s_waitcnt lgkmcnt(0)" ::: "memory")

__global__ __launch_bounds__(256, 4) void sparse_attn(
    const float* __restrict__ qkv, float* __restrict__ aout)
{
    __shared__ __align__(16) float  sbuf[QB * SSTR];        // 32.1 KB scores / p-values
    __shared__ __align__(16) unsigned int hist[QB * 256];   // 4 KB
    __shared__ unsigned int prefS[QB];
    __shared__ int   remS[QB];
    __shared__ float zS[QB];

    const int tid = threadIdx.x;
    const int w   = tid >> 6;       // wave id = row id (0..3) = column-range owner
    const int l   = tid & 63;
    const int p   = l & 3;          // quad lane: dims [4p,4p+4) and [16+4p,16+4p+4)
    const int jg  = l >> 2;         // 0..15 = row within a 16-row tile

    const int blk = blockIdx.x;
    const int nqb = NSEQ / QB;      // 512
    const int bh  = blk / nqb;
    const int qblk = blk % nqb;
    const int b = bh / NHEADS, h = bh % NHEADS;
    const int n0 = qblk * QB;

    const float* base = qkv + (size_t)b * NSEQ * 768;
    // this thread's K/V column pointers: column = 512w + t*16 + jg, dims 4p + {0,16}
    const float* kptr = base + 256 + h * 32 + p * 4 + (size_t)((w << 9) + jg) * 768;
    const float* vptr = base + 512 + h * 32 + p * 4 + (size_t)((w << 9) + jg) * 768;
#define KADDR(t) (kptr + (size_t)(t) * (16 * 768))
#define VADDR(t) (vptr + (size_t)(t) * (16 * 768))

    // ---- Q rows 0..3, this lane's dim chunks [4p,4p+4) & [16+4p,..), scaled ----
    float4 qa[QB], qc[QB];
    {
        const float* gq = base + (size_t)n0 * 768 + h * 32 + p * 4;
        #pragma unroll
        for (int r = 0; r < QB; ++r) {
            float4 x0 = *(const float4*)(gq + (size_t)r * 768);
            float4 x1 = *(const float4*)(gq + (size_t)r * 768 + 16);
            qa[r].x = x0.x * ATTN_SCALE; qa[r].y = x0.y * ATTN_SCALE;
            qa[r].z = x0.z * ATTN_SCALE; qa[r].w = x0.w * ATTN_SCALE;
            qc[r].x = x1.x * ATTN_SCALE; qc[r].y = x1.y * ATTN_SCALE;
            qc[r].z = x1.z * ATTN_SCALE; qc[r].w = x1.w * ATTN_SCALE;
        }
    }
    // zero pass-3 histogram (filled inline during phase B by all waves)
    {
        uint4 z4; z4.x = 0u; z4.y = 0u; z4.z = 0u; z4.w = 0u;
        *(uint4*)(hist + tid * 4) = z4;
    }
    if (tid < QB) { prefS[tid] = 0u; remS[tid] = NKEEP; }
    RBAR();   // barrier 1: hist/prefS initialized before any atomic

    // per-tile score computation: K chunk regs -> 4 row scores -> sbuf + hist
#define QK_TILE(K0, K1, T) do {                                               \
        float sc0 = qa[0].x*(K0).x + qa[0].y*(K0).y + qa[0].z*(K0).z + qa[0].w*(K0).w \
                  + qc[0].x*(K1).x + qc[0].y*(K1).y + qc[0].z*(K1).z + qc[0].w*(K1).w; \
        float sc1 = qa[1].x*(K0).x + qa[1].y*(K0).y + qa[1].z*(K0).z + qa[1].w*(K0).w \
                  + qc[1].x*(K1).x + qc[1].y*(K1).y + qc[1].z*(K1).z + qc[1].w*(K1).w; \
        float sc2 = qa[2].x*(K0).x + qa[2].y*(K0).y + qa[2].z*(K0).z + qa[2].w*(K0).w \
                  + qc[2].x*(K1).x + qc[2].y*(K1).y + qc[2].z*(K1).z + qc[2].w*(K1).w; \
        float sc3 = qa[3].x*(K0).x + qa[3].y*(K0).y + qa[3].z*(K0).z + qa[3].w*(K0).w \
                  + qc[3].x*(K1).x + qc[3].y*(K1).y + qc[3].z*(K1).z + qc[3].w*(K1).w; \
        sc0 = dpp_xor2_add(dpp_xor1_add(sc0));                                \
        sc1 = dpp_xor2_add(dpp_xor1_add(sc1));                                \
        sc2 = dpp_xor2_add(dpp_xor1_add(sc2));                                \
        sc3 = dpp_xor2_add(dpp_xor1_add(sc3));                                \
        float myv = (p == 0) ? sc0 : (p == 1) ? sc1 : (p == 2) ? sc2 : sc3;   \
        const int col = (w << 9) + ((T) << 4) + jg;                           \
        sbuf[p * SSTR + col] = myv;                                           \
        atomicAdd(&hist[p * 256 + (f2key(myv) >> 24)], 1u);                   \
    } while (0)

    // ---- Phase B: scores + top-byte histogram. 4-deep register pipeline. ----
    float4 ka0 = *(const float4*)(KADDR(0)), ka1 = *(const float4*)(KADDR(0) + 16);
    float4 kb0 = *(const float4*)(KADDR(1)), kb1 = *(const float4*)(KADDR(1) + 16);
    float4 kc0 = *(const float4*)(KADDR(2)), kc1 = *(const float4*)(KADDR(2) + 16);
    float4 kd0 = *(const float4*)(KADDR(3)), kd1 = *(const float4*)(KADDR(3) + 16);
    #pragma unroll 1
    for (int t = 0; t < NT2; t += 4) {
        float4 c0, c1;
        c0 = ka0; c1 = ka1;
        if (t + 4 < NT2) { ka0 = *(const float4*)(KADDR(t + 4)); ka1 = *(const float4*)(KADDR(t + 4) + 16); }
        QK_TILE(c0, c1, t);
        c0 = kb0; c1 = kb1;
        if (t + 5 < NT2) { kb0 = *(const float4*)(KADDR(t + 5)); kb1 = *(const float4*)(KADDR(t + 5) + 16); }
        QK_TILE(c0, c1, t + 1);
        c0 = kc0; c1 = kc1;
        if (t + 6 < NT2) { kc0 = *(const float4*)(KADDR(t + 6)); kc1 = *(const float4*)(KADDR(t + 6) + 16); }
        QK_TILE(c0, c1, t + 2);
        c0 = kd0; c1 = kd1;
        if (t + 7 < NT2) { kd0 = *(const float4*)(KADDR(t + 7)); kd1 = *(const float4*)(KADDR(t + 7) + 16); }
        QK_TILE(c0, c1, t + 3);
    }
    // preload V tiles 0..3 into registers; latency hides under radix/softmax
    float4 va0 = *(const float4*)(VADDR(0)), va1 = *(const float4*)(VADDR(0) + 16);
    float4 vb0 = *(const float4*)(VADDR(1)), vb1 = *(const float4*)(VADDR(1) + 16);
    float4 vc0 = *(const float4*)(VADDR(2)), vc1 = *(const float4*)(VADDR(2) + 16);
    float4 vd0 = *(const float4*)(VADDR(3)), vd1 = *(const float4*)(VADDR(3) + 16);
    RBAR();   // barrier 2: all scores + histogram atomics visible

    // ---- Phase C: exact 614th-largest per row. Wave w owns row w only. ----
    unsigned int* hrow = hist + w * 256;
    #pragma unroll 1
    for (int pass = 3; pass >= 0; --pass) {
        const int sh = pass * 8;
        const unsigned int pr = prefS[w];
        const int remv = remS[w];
        if (pass != 3) {
            const unsigned int hmsk = 0xFFFFFFFFu << (sh + 8);
            uint4 z4; z4.x = 0u; z4.y = 0u; z4.z = 0u; z4.w = 0u;
            *(uint4*)(hrow + l * 4) = z4;
            LGKM0();
            #pragma unroll 2
            for (int e = 0; e < 8; ++e) {
                float4 v = *(const float4*)&sbuf[w * SSTR + l * 4 + 256 * e];
                unsigned int k0 = f2key(v.x), k1 = f2key(v.y), k2 = f2key(v.z), k3 = f2key(v.w);
                if ((k0 & hmsk) == pr) atomicAdd(&hrow[(k0 >> sh) & 255u], 1u);
                if ((k1 & hmsk) == pr) atomicAdd(&hrow[(k1 >> sh) & 255u], 1u);
                if ((k2 & hmsk) == pr) atomicAdd(&hrow[(k2 >> sh) & 255u], 1u);
                if ((k3 & hmsk) == pr) atomicAdd(&hrow[(k3 >> sh) & 255u], 1u);
            }
            LGKM0();
        }
        uint4 c4 = *(const uint4*)(hrow + l * 4);
        unsigned int cnt[4] = { c4.x, c4.y, c4.z, c4.w };
        unsigned int part = cnt[0] + cnt[1] + cnt[2] + cnt[3];
        unsigned int suf = part;
        #pragma unroll
        for (int dlt = 1; dlt < 64; dlt <<= 1) {
            unsigned int v = __shfl_down(suf, dlt);
            if (l + dlt < 64) suf += v;
        }
        unsigned int run = suf - part;   // elems in bins owned by lanes > l
        #pragma unroll
        for (int i = 3; i >= 0; --i) {
            if ((int)run < remv && remv <= (int)(run + cnt[i])) {
                remS[w]  = remv - (int)run;
                prefS[w] = pr | ((unsigned int)(l * 4 + i) << sh);
            }
            run += cnt[i];
        }
        LGKM0();  // pref/rem visible wave-wide before next pass
    }

    // ---- Phase D: masked softmax on row w (float4, in LDS) ----
    {
        unsigned int key = prefS[w];
        unsigned int u = (key & 0x80000000u) ? (key & 0x7FFFFFFFu) : ~key;
        const float thr = __uint_as_float(u);
        float mx = 0.f;   // >=1434 masked zeros always present
        #pragma unroll 2
        for (int e = 0; e < 8; ++e) {
            float* sp = &sbuf[w * SSTR + l * 4 + 256 * e];
            float4 v = *(const float4*)sp;
            v.x = (v.x >= thr) ? v.x : 0.f;
            v.y = (v.y >= thr) ? v.y : 0.f;
            v.z = (v.z >= thr) ? v.z : 0.f;
            v.w = (v.w >= thr) ? v.w : 0.f;
            *(float4*)sp = v;
            mx = fmaxf(mx, fmaxf(fmaxf(v.x, v.y), fmaxf(v.z, v.w)));
        }
        #pragma unroll
        for (int d2 = 32; d2 >= 1; d2 >>= 1) mx = fmaxf(mx, __shfl_xor(mx, d2));
        float Z = 0.f;
        const float cm = __expf(0.f - mx);   // masked-entry value
        if (thr > 0.f) {
            // kept values >= thr > 0, masked == 0 exactly -> v>0 discriminates
            #pragma unroll 2
            for (int e = 0; e < 8; ++e) {
                float* sp = &sbuf[w * SSTR + l * 4 + 256 * e];
                float4 v = *(const float4*)sp;
                v.x = (v.x > 0.f) ? __expf(v.x - mx) : cm;
                v.y = (v.y > 0.f) ? __expf(v.y - mx) : cm;
                v.z = (v.z > 0.f) ? __expf(v.z - mx) : cm;
                v.w = (v.w > 0.f) ? __expf(v.w - mx) : cm;
                *(float4*)sp = v;
                Z += v.x + v.y + v.z + v.w;
            }
        } else {
            #pragma unroll 2
            for (int e = 0; e < 8; ++e) {
                float* sp = &sbuf[w * SSTR + l * 4 + 256 * e];
                float4 v = *(const float4*)sp;
                v.x = __expf(v.x - mx); v.y = __expf(v.y - mx);
                v.z = __expf(v.z - mx); v.w = __expf(v.w - mx);
                *(float4*)sp = v;
                Z += v.x + v.y + v.z + v.w;
            }
        }
        #pragma unroll
        for (int d2 = 32; d2 >= 1; d2 >>= 1) Z += __shfl_xor(Z, d2);
        if (l == 0) zS[w] = Z;
    }
    RBAR();   // barrier 3: all rows' p-values + zS visible

    // ---- Phase E: PV. 4-deep register pipeline over V, no barriers. ----
    float4 oa0, oa1, oa2, oa3, ob0, ob1, ob2, ob3;
    oa0.x=0;oa0.y=0;oa0.z=0;oa0.w=0; ob0=oa0; oa1=oa0; ob1=oa0;
    oa2=oa0; ob2=oa0; oa3=oa0; ob3=oa0;

#define PV_TILE(V0, V1, T) do {                                               \
        const int col = (w << 9) + ((T) << 4) + jg;                           \
        float p0 = sbuf[0 * SSTR + col];                                      \
        float p1 = sbuf[1 * SSTR + col];                                      \
        float p2 = sbuf[2 * SSTR + col];                                      \
        float p3 = sbuf[3 * SSTR + col];                                      \
        oa0.x=fmaf(p0,(V0).x,oa0.x); oa0.y=fmaf(p0,(V0).y,oa0.y); oa0.z=fmaf(p0,(V0).z,oa0.z); oa0.w=fmaf(p0,(V0).w,oa0.w); \
        ob0.x=fmaf(p0,(V1).x,ob0.x); ob0.y=fmaf(p0,(V1).y,ob0.y); ob0.z=fmaf(p0,(V1).z,ob0.z); ob0.w=fmaf(p0,(V1).w,ob0.w); \
        oa1.x=fmaf(p1,(V0).x,oa1.x); oa1.y=fmaf(p1,(V0).y,oa1.y); oa1.z=fmaf(p1,(V0).z,oa1.z); oa1.w=fmaf(p1,(V0).w,oa1.w); \
        ob1.x=fmaf(p1,(V1).x,ob1.x); ob1.y=fmaf(p1,(V1).y,ob1.y); ob1.z=fmaf(p1,(V1).z,ob1.z); ob1.w=fmaf(p1,(V1).w,ob1.w); \
        oa2.x=fmaf(p2,(V0).x,oa2.x); oa2.y=fmaf(p2,(V0).y,oa2.y); oa2.z=fmaf(p2,(V0).z,oa2.z); oa2.w=fmaf(p2,(V0).w,oa2.w); \
        ob2.x=fmaf(p2,(V1).x,ob2.x); ob2.y=fmaf(p2,(V1).y,ob2.y); ob2.z=fmaf(p2,(V1).z,ob2.z); ob2.w=fmaf(p2,(V1).w,ob2.w); \
        oa3.x=fmaf(p3,(V0).x,oa3.x); oa3.y=fmaf(p3,(V0).y,oa3.y); oa3.z=fmaf(p3,(V0).z,oa3.z); oa3.w=fmaf(p3,(V0).w,oa3.w); \
        ob3.x=fmaf(p3,(V1).x,ob3.x); ob3.y=fmaf(p3,(V1).y,ob3.y); ob3.z=fmaf(p3,(V1).z,ob3.z); ob3.w=fmaf(p3,(V1).w,ob3.w); \
    } while (0)

    #pragma unroll 1
    for (int t = 0; t < NT2; t += 4) {
        float4 c0, c1;
        c0 = va0; c1 = va1;
        if (t + 4 < NT2) { va0 = *(const float4*)(VADDR(t + 4)); va1 = *(const float4*)(VADDR(t + 4) + 16); }
        PV_TILE(c0, c1, t);
        c0 = vb0; c1 = vb1;
        if (t + 5 < NT2) { vb0 = *(const float4*)(VADDR(t + 5)); vb1 = *(const float4*)(VADDR(t + 5) + 16); }
        PV_TILE(c0, c1, t + 1);
        c0 = vc0; c1 = vc1;
        if (t + 6 < NT2) { vc0 = *(const float4*)(VADDR(t + 6)); vc1 = *(const float4*)(VADDR(t + 6) + 16); }
        PV_TILE(c0, c1, t + 2);
        c0 = vd0; c1 = vd1;
        if (t + 7 < NT2) { vd0 = *(const float4*)(VADDR(t + 7)); vd1 = *(const float4*)(VADDR(t + 7) + 16); }
        PV_TILE(c0, c1, t + 3);
    }
    RBAR();   // barrier 4: all p-value reads done; sbuf reusable as partials

    // reduce over the 16 column-groups (lanes differing in bits 2..5)
    #pragma unroll
    for (int d2 = 4; d2 <= 32; d2 <<= 1) {
        oa0.x+=__shfl_xor(oa0.x,d2); oa0.y+=__shfl_xor(oa0.y,d2); oa0.z+=__shfl_xor(oa0.z,d2); oa0.w+=__shfl_xor(oa0.w,d2);
        ob0.x+=__shfl_xor(ob0.x,d2); ob0.y+=__shfl_xor(ob0.y,d2); ob0.z+=__shfl_xor(ob0.z,d2); ob0.w+=__shfl_xor(ob0.w,d2);
        oa1.x+=__shfl_xor(oa1.x,d2); oa1.y+=__shfl_xor(oa1.y,d2); oa1.z+=__shfl_xor(oa1.z,d2); oa1.w+=__shfl_xor(oa1.w,d2);
        ob1.x+=__shfl_xor(ob1.x,d2); ob1.y+=__shfl_xor(ob1.y,d2); ob1.z+=__shfl_xor(ob1.z,d2); ob1.w+=__shfl_xor(ob1.w,d2);
        oa2.x+=__shfl_xor(oa2.x,d2); oa2.y+=__shfl_xor(oa2.y,d2); oa2.z+=__shfl_xor(oa2.z,d2); oa2.w+=__shfl_xor(oa2.w,d2);
        ob2.x+=__shfl_xor(ob2.x,d2); ob2.y+=__shfl_xor(ob2.y,d2); ob2.z+=__shfl_xor(ob2.z,d2); ob2.w+=__shfl_xor(ob2.w,d2);
        oa3.x+=__shfl_xor(oa3.x,d2); oa3.y+=__shfl_xor(oa3.y,d2); oa3.z+=__shfl_xor(oa3.z,d2); oa3.w+=__shfl_xor(oa3.w,d2);
        ob3.x+=__shfl_xor(ob3.x,d2); ob3.y+=__shfl_xor(ob3.y,d2); ob3.z+=__shfl_xor(ob3.z,d2); ob3.w+=__shfl_xor(ob3.w,d2);
    }
    // lanes 0..3 of each wave hold dims [4l,4l+4) (oa) and [16+4l,..) (ob)
    if (l < 4) {
        float* part = &sbuf[0];   // [4 waves][4 rows][32 dims]
        *(float4*)&part[(w * 4 + 0) * 32 + l * 4]      = oa0;
        *(float4*)&part[(w * 4 + 0) * 32 + 16 + l * 4] = ob0;
        *(float4*)&part[(w * 4 + 1) * 32 + l * 4]      = oa1;
        *(float4*)&part[(w * 4 + 1) * 32 + 16 + l * 4] = ob1;
        *(float4*)&part[(w * 4 + 2) * 32 + l * 4]      = oa2;
        *(float4*)&part[(w * 4 + 2) * 32 + 16 + l * 4] = ob2;
        *(float4*)&part[(w * 4 + 3) * 32 + l * 4]      = oa3;
        *(float4*)&part[(w * 4 + 3) * 32 + 16 + l * 4] = ob3;
    }
    RBAR();   // barrier 5
    if (tid < 128) {
        const int r = tid >> 5, d = tid & 31;
        const float* part = &sbuf[0];
        float o = part[(0 * 4 + r) * 32 + d] + part[(1 * 4 + r) * 32 + d]
                + part[(2 * 4 + r) * 32 + d] + part[(3 * 4 + r) * 32 + d];
        o /= zS[r];
        aout[((size_t)b * NSEQ + n0 + r) * CDIM + h * 32 + d] = o;
    }
}

// -------------------------------------------------------------------------
extern "C" void kernel_launch(void* const* d_in, const int* in_sizes, int n_in,
                              void* d_out, int out_size, void* d_ws, size_t ws_size,
                              hipStream_t stream) {
    (void)in_sizes; (void)n_in; (void)out_size; (void)ws_size;
    const float* x      = (const float*)d_in[0];
    const float* w_qkv  = (const float*)d_in[1];
    const float* b_qkv  = (const float*)d_in[2];
    const float* w_proj = (const float*)d_in[3];
    const float* b_proj = (const float*)d_in[4];
    float* out = (float*)d_out;

    const int M = BDIM * NSEQ;  // 8192
    float* qkv_ws  = (float*)d_ws;                       // 25.2 MB
    float* attn_ws = qkv_ws + (size_t)M * 768;           // 8.4 MB

    // 1) QKV GEMM -> [B][N][3][H][D]
    dim3 g1(M / 64, 768 / 64);
    gemm_nt_bias<<<g1, 256, 0, stream>>>(x, w_qkv, b_qkv, qkv_ws, M, 768, 256);

    // 2) fused sparse attention -> [B][N][C]
    sparse_attn<<<BDIM * NHEADS * (NSEQ / QB), 256, 0, stream>>>(qkv_ws, attn_ws);

    // 3) projection GEMM -> d_out
    dim3 g2(M / 64, 256 / 64);
    gemm_nt_bias<<<g2, 256, 0, stream>>>(attn_ws, w_proj, b_proj, out, M, 256, 256);
}